// Round 10
// baseline (3054.514 us; speedup 1.0000x reference)
//
#include <hip/hip_runtime.h>
#include <hip/hip_bf16.h>
#include <hip/hip_cooperative_groups.h>

namespace cg = cooperative_groups;

#define N_NODES 50000
#define N_EDGES 800000
#define D 64
#define VROWS 50048     // 782 tiles * 64 rows (nodemm unmasked A-loads)
#define NRANGE 8        // src ranges; slice = 6250*128B = 0.8 MB << 4 MiB L2
#define RSIZE 6250
#define NT2 (N_NODES * NRANGE)            // 400000 buckets
#define NB2 ((NT2 + 2047) / 2048)         // 196 scan chunks
#define GRID_A 1024
#define WAVES_A (GRID_A * 4)              // 4096
#define NPW ((N_NODES + WAVES_A - 1) / WAVES_A)   // 13 nodes/wave
#define ECHUNKS ((N_EDGES + 255) / 256)   // 3125

typedef __hip_bfloat16 bf16;
typedef __bf16 bf16x8 __attribute__((ext_vector_type(8)));
typedef float  f32x4  __attribute__((ext_vector_type(4)));

__device__ __forceinline__ float bu2f(unsigned short u) {
    unsigned int w = ((unsigned int)u) << 16;
    return __builtin_bit_cast(float, w);
}
__device__ __forceinline__ unsigned short f2bu(float f) {
    bf16 h = __float2bfloat16(f);           // RTNE
    return __builtin_bit_cast(unsigned short, h);
}
__device__ __forceinline__ float ldf(const void* p, size_t i, bool f32mode) {
    if (f32mode) return ((const float*)p)[i];
    return bu2f(((const unsigned short*)p)[i]);
}
__device__ __forceinline__ void stf(void* p, size_t i, float v, bool f32mode) {
    if (f32mode) ((float*)p)[i] = v;
    else ((unsigned short*)p)[i] = f2bu(v);
}
__device__ __forceinline__ int ldidx(const int* ei, size_t e, int row, bool i64mode) {
    if (i64mode) return ei[((size_t)row * N_EDGES + e) * 2];  // low word, LE
    return ei[(size_t)row * N_EDGES + e];
}
__device__ __forceinline__ void unpack8(uint4 v, float* f) {
    f[0] = bu2f(v.x & 0xffff); f[1] = bu2f(v.x >> 16);
    f[2] = bu2f(v.y & 0xffff); f[3] = bu2f(v.y >> 16);
    f[4] = bu2f(v.z & 0xffff); f[5] = bu2f(v.z >> 16);
    f[6] = bu2f(v.w & 0xffff); f[7] = bu2f(v.w >> 16);
}

// ---------------------------------------------------------------------------
// coopA: detect + zero + hist2 + 3-stage scan + fill2 + PHASED gather.
// CSR bucketed by (dst, src-range). Gather phase p touches only x rows in
// range p (0.8 MB slice -> L2-resident on every XCD); per-wave f32
// accumulators live in registers across grid.sync().
// NO early returns anywhere (every thread must reach every grid.sync).
// ---------------------------------------------------------------------------
__global__ __launch_bounds__(256, 4) void coopA_kernel(
    const void* x, const int* ei,
    const void* W2, const void* b1, const void* b2,
    int* flags, unsigned short* w2bf, float* b1f, float* b2fp,
    int* counts2, int* off2, int* cursor2, int* partials,
    int* sarr, int* earr, unsigned short* vtab)
{
    cg::grid_group grid = cg::this_grid();
    const int b   = blockIdx.x;
    const int tid = threadIdx.x;
    const int G   = gridDim.x;          // GRID_A
    __shared__ int lds[256];

    // ---- phase 0: detect (block 0, wave 0) + zero counts2 (all) ----
    if (b == 0 && tid < 64) {
        int lane = tid;
        const unsigned short* u = (const unsigned short*)x;
        int weird = 0, zeros = 0;
        for (int k = lane; k < 128; k += 64) {
            int ex = (u[2 * k] >> 7) & 0xFF;
            if (ex < 90 || ex > 160) ++weird;
            if (ei[2 * k + 1] == 0) ++zeros;
        }
        #pragma unroll
        for (int off = 1; off < 64; off <<= 1) {
            weird += __shfl_xor(weird, off, 64);
            zeros += __shfl_xor(zeros, off, 64);
        }
        bool f32 = (weird > 32);
        if (lane == 0) {
            flags[0] = f32 ? 1 : 0;
            flags[1] = (zeros > 120) ? 1 : 0;
            b2fp[0] = ldf(b2, 0, f32);
        }
        w2bf[lane] = f2bu(ldf(W2, lane, f32));
        b1f[lane]  = ldf(b1, lane, f32);
    }
    for (int i = b * 256 + tid; i < NT2; i += G * 256) counts2[i] = 0;
    grid.sync();

    const bool f32m = flags[0] != 0;
    const bool i64m = flags[1] != 0;

    // ---- phase 1: hist2, XCD-sharded by dst chunk (proven R6 trick) ----
    {
        int grp = b & 7;
        for (int c = b >> 3; c < ECHUNKS; c += (G >> 3)) {
            int e = c * 256 + tid;
            if (e < N_EDGES) {
                int d = ldidx(ei, e, 1, i64m);
                if (((d >> 6) & 7) == grp) {
                    int s = ldidx(ei, e, 0, i64m);
                    atomicAdd(&counts2[d * 8 + s / RSIZE], 1);
                }
            }
        }
    }
    grid.sync();

    // ---- phase 2: scan1 — 2048-elem chunk sums -> partials[NB2] ----
    for (int c = b; c < NB2; c += G) {
        int base = c * 2048 + tid * 8;
        int sum = 0;
        #pragma unroll
        for (int k = 0; k < 8; ++k) {
            int i = base + k;
            sum += (i < NT2) ? counts2[i] : 0;
        }
        #pragma unroll
        for (int off = 1; off < 64; off <<= 1) sum += __shfl_xor(sum, off, 64);
        if ((tid & 63) == 0) lds[tid >> 6] = sum;
        __syncthreads();
        if (tid == 0) partials[c] = lds[0] + lds[1] + lds[2] + lds[3];
        __syncthreads();
    }
    grid.sync();

    // ---- phase 3: scan2 — block 0 exclusive-scans partials ----
    if (b == 0) {
        int v = (tid < NB2) ? partials[tid] : 0;
        lds[tid] = v;
        __syncthreads();
        for (int off = 1; off < 256; off <<= 1) {
            int t = (tid >= off) ? lds[tid - off] : 0;
            __syncthreads();
            lds[tid] += t;
            __syncthreads();
        }
        if (tid < NB2) partials[tid] = lds[tid] - v;   // exclusive chunk base
    }
    grid.sync();

    // ---- phase 4: scan3 — per-chunk scan, write off2 + cursor2 ----
    for (int c = b; c < NB2; c += G) {
        int base = c * 2048 + tid * 8;
        int loc[8];
        int sum = 0;
        #pragma unroll
        for (int k = 0; k < 8; ++k) {
            int i = base + k;
            loc[k] = (i < NT2) ? counts2[i] : 0;
            sum += loc[k];
        }
        int incl = sum;
        #pragma unroll
        for (int off = 1; off < 64; off <<= 1) {
            int t = __shfl_up(incl, off, 64);
            if ((tid & 63) >= off) incl += t;
        }
        if ((tid & 63) == 63) lds[tid >> 6] = incl;
        __syncthreads();
        int wv = tid >> 6, wbase = 0;
        #pragma unroll
        for (int q = 0; q < 4; ++q) if (q < wv) wbase += lds[q];
        __syncthreads();
        int run = partials[c] + wbase + incl - sum;   // global exclusive
        #pragma unroll
        for (int k = 0; k < 8; ++k) {
            int i = base + k;
            if (i < NT2) { off2[i] = run; cursor2[i] = run; run += loc[k]; }
        }
    }
    if (b == 0 && tid == 0) off2[NT2] = N_EDGES;
    grid.sync();

    // ---- phase 5: fill2, XCD-sharded ----
    {
        int grp = b & 7;
        for (int c = b >> 3; c < ECHUNKS; c += (G >> 3)) {
            int e = c * 256 + tid;
            if (e < N_EDGES) {
                int d = ldidx(ei, e, 1, i64m);
                if (((d >> 6) & 7) == grp) {
                    int s = ldidx(ei, e, 0, i64m);
                    int pos = atomicAdd(&cursor2[d * 8 + s / RSIZE], 1);
                    sarr[pos] = s;
                    earr[pos] = e;
                }
            }
        }
    }
    grid.sync();

    // ---- phases 6..13: gather over src ranges, one range per grid phase ----
    {
        int wgid = b * 4 + (tid >> 6);
        int lane = tid & 63;
        float acc[NPW];
        #pragma unroll
        for (int i = 0; i < NPW; ++i) {
            int w = wgid + i * WAVES_A;
            acc[i] = (w < N_NODES) ? ldf(x, (size_t)w * D + lane, f32m) : 0.f;
        }
        for (int p = 0; p < NRANGE; ++p) {
            #pragma unroll
            for (int i = 0; i < NPW; ++i) {
                int w = wgid + i * WAVES_A;
                if (w < N_NODES) {
                    int beg = off2[w * 8 + p];
                    int end = off2[w * 8 + p + 1];
                    float t0 = 0.f, t1 = 0.f;
                    int j = beg;
                    for (; j + 2 <= end; j += 2) {
                        int s0 = sarr[j], s1 = sarr[j + 1];
                        t0 += ldf(x, (size_t)s0 * D + lane, f32m);
                        t1 += ldf(x, (size_t)s1 * D + lane, f32m);
                    }
                    if (j < end) t0 += ldf(x, (size_t)sarr[j] * D + lane, f32m);
                    acc[i] += t0 + t1;
                }
            }
            grid.sync();
        }
        #pragma unroll
        for (int i = 0; i < NPW; ++i) {
            int w = wgid + i * WAVES_A;
            if (w < N_NODES) vtab[(size_t)w * D + lane] = f2bu(acc[i]);
        }
    }
}

// ---------------------------------------------------------------------------
// nodemm: MFMA node transform, one wave = 16 nodes (proven R4-R9, unchanged).
// vtab aliases p_src: each wave reads its own 16 rows before overwriting.
// ---------------------------------------------------------------------------
__global__ __launch_bounds__(256) void nodemm_kernel(
    const unsigned short* vtab,
    const void* __restrict__ W_enc, const void* __restrict__ b_enc,
    const void* __restrict__ W1,
    unsigned short* p_src, unsigned short* p_dst,
    const float* __restrict__ b1f, const int* __restrict__ flags)
{
    __shared__ unsigned short wtWe[64 * 72];
    __shared__ unsigned short wtWa[64 * 72];
    __shared__ unsigned short wtWb[64 * 72];
    __shared__ float benc[64];
    __shared__ unsigned short ebuf[4][16 * 72];

    bool f32m = flags[0] != 0;
    int tid = threadIdx.x;
    for (int t = tid; t < 4096; t += 256) {
        int i = t >> 6, j = t & 63;             // W[i][j], i=k(in), j=n(out)
        wtWe[j * 72 + i] = f2bu(ldf(W_enc, t, f32m));
        wtWa[j * 72 + i] = f2bu(ldf(W1, t, f32m));
        wtWb[j * 72 + i] = f2bu(ldf(W1, 4096 + t, f32m));
    }
    if (tid < 64) benc[tid] = ldf(b_enc, tid, f32m);
    __syncthreads();

    int wave = tid >> 6;
    int lane = tid & 63;
    int lo   = lane & 15;
    int quad = lane >> 4;
    unsigned short* eb = ebuf[wave];
    int base = blockIdx.x * 64 + wave * 16;

    bf16x8 av0 = *(const bf16x8*)&vtab[(size_t)(base + lo) * D + quad * 8];
    bf16x8 av1 = *(const bf16x8*)&vtab[(size_t)(base + lo) * D + 32 + quad * 8];

    f32x4 z = {0.f, 0.f, 0.f, 0.f};
    f32x4 acc1[4] = {z, z, z, z};
    #pragma unroll
    for (int nt = 0; nt < 4; ++nt) {
        bf16x8 b0  = *(const bf16x8*)&wtWe[(nt * 16 + lo) * 72 + quad * 8];
        bf16x8 b1v = *(const bf16x8*)&wtWe[(nt * 16 + lo) * 72 + 32 + quad * 8];
        acc1[nt] = __builtin_amdgcn_mfma_f32_16x16x32_bf16(av0, b0, acc1[nt], 0, 0, 0);
        acc1[nt] = __builtin_amdgcn_mfma_f32_16x16x32_bf16(av1, b1v, acc1[nt], 0, 0, 0);
    }
    #pragma unroll
    for (int nt = 0; nt < 4; ++nt) {
        float bias = benc[nt * 16 + lo];
        #pragma unroll
        for (int r = 0; r < 4; ++r) {
            int m = quad * 4 + r;
            float ev = fmaxf(acc1[nt][r] + bias, 0.f);
            eb[m * 72 + nt * 16 + lo] = f2bu(ev);
        }
    }

    bf16x8 ae0 = *(const bf16x8*)&eb[lo * 72 + quad * 8];
    bf16x8 ae1 = *(const bf16x8*)&eb[lo * 72 + 32 + quad * 8];

    f32x4 acc2[4] = {z, z, z, z};
    f32x4 acc3[4] = {z, z, z, z};
    #pragma unroll
    for (int nt = 0; nt < 4; ++nt) {
        bf16x8 ba0 = *(const bf16x8*)&wtWa[(nt * 16 + lo) * 72 + quad * 8];
        bf16x8 ba1 = *(const bf16x8*)&wtWa[(nt * 16 + lo) * 72 + 32 + quad * 8];
        bf16x8 bb0 = *(const bf16x8*)&wtWb[(nt * 16 + lo) * 72 + quad * 8];
        bf16x8 bb1 = *(const bf16x8*)&wtWb[(nt * 16 + lo) * 72 + 32 + quad * 8];
        acc2[nt] = __builtin_amdgcn_mfma_f32_16x16x32_bf16(ae0, ba0, acc2[nt], 0, 0, 0);
        acc2[nt] = __builtin_amdgcn_mfma_f32_16x16x32_bf16(ae1, ba1, acc2[nt], 0, 0, 0);
        acc3[nt] = __builtin_amdgcn_mfma_f32_16x16x32_bf16(ae0, bb0, acc3[nt], 0, 0, 0);
        acc3[nt] = __builtin_amdgcn_mfma_f32_16x16x32_bf16(ae1, bb1, acc3[nt], 0, 0, 0);
    }
    #pragma unroll
    for (int nt = 0; nt < 4; ++nt) {
        float b1v = b1f[nt * 16 + lo];
        #pragma unroll
        for (int r = 0; r < 4; ++r) {
            int node = base + quad * 4 + r;
            if (node < N_NODES) {
                size_t idx = (size_t)node * D + nt * 16 + lo;
                p_src[idx] = f2bu(acc2[nt][r] + b1v);   // fold b1
                p_dst[idx] = f2bu(acc3[nt][r]);
            }
        }
    }
}

// ---------------------------------------------------------------------------
// coopB: PHASED edge scorer. Phase p: all waves process in-edges whose src is
// in range p -> p_src slice (0.8 MB) L2-resident everywhere. 8 lanes/edge.
// ---------------------------------------------------------------------------
__global__ __launch_bounds__(256, 4) void coopB_kernel(
    const unsigned short* p_src, const unsigned short* p_dst,
    const int* off2, const int* sarr, const int* earr,
    const unsigned short* w2bf, const float* b2fp,
    void* out, const int* flags)
{
    cg::grid_group grid = cg::this_grid();
    bool f32m = flags[0] != 0;
    int b = blockIdx.x, tid = threadIdx.x;
    int wgid = b * 4 + (tid >> 6);
    int lane = tid & 63;
    int sub = lane & 7;    // feature chunk (8 feats)
    int g   = lane >> 3;   // edge slot (8 edges/round)

    uint4 w2v = ((const uint4*)w2bf)[sub];
    float w2[8];
    unpack8(w2v, w2);
    float bb = b2fp[0];

    for (int p = 0; p < NRANGE; ++p) {
        for (int i = 0; i < NPW; ++i) {
            int w = wgid + i * WAVES_A;
            if (w < N_NODES) {
                int beg = off2[w * 8 + p];
                int end = off2[w * 8 + p + 1];
                if (beg < end) {
                    uint4 pdv = ((const uint4*)p_dst)[(size_t)w * 8 + sub];
                    float pd[8];
                    unpack8(pdv, pd);
                    for (int pos0 = beg; pos0 < end; pos0 += 8) {
                        int pos = pos0 + g;
                        bool ok = pos < end;
                        int idx = ok ? pos : beg;
                        int s = sarr[idx];
                        uint4 psv = ((const uint4*)p_src)[(size_t)s * 8 + sub];
                        float ps[8];
                        unpack8(psv, ps);
                        float c = 0.f;
                        #pragma unroll
                        for (int k = 0; k < 8; ++k)
                            c += fmaxf(ps[k] + pd[k], 0.f) * w2[k];
                        c += __shfl_xor(c, 1, 64);
                        c += __shfl_xor(c, 2, 64);
                        c += __shfl_xor(c, 4, 64);
                        if (sub == 0 && ok) stf(out, earr[pos], c + bb, f32m);
                    }
                }
            }
        }
        grid.sync();
    }
}

// ---------------------------------------------------------------------------
extern "C" void kernel_launch(void* const* d_in, const int* in_sizes, int n_in,
                              void* d_out, int out_size, void* d_ws, size_t ws_size,
                              hipStream_t stream)
{
    const void* x     = d_in[0];
    const int*  ei    = (const int*)d_in[1];
    const void* W_enc = d_in[2];
    const void* b_enc = d_in[3];
    const void* W1    = d_in[4];
    const void* b1    = d_in[5];
    const void* W2    = d_in[6];
    const void* b2    = d_in[7];

    const size_t NTv = (size_t)VROWS * D;   // 3,203,072 elements
    // ws layout (~24.2 MB):
    unsigned short* p_src = (unsigned short*)d_ws;       // 6.41 MB (aliases vtab)
    unsigned short* p_dst = p_src + NTv;                 // 6.41 MB
    int*   sarr    = (int*)(p_dst + NTv);                // 3.2 MB
    int*   earr    = sarr + N_EDGES;                     // 3.2 MB
    int*   counts2 = earr + N_EDGES;                     // 1.6 MB
    int*   off2    = counts2 + NT2;                      // 1.6 MB (+1)
    int*   cursor2 = off2 + NT2 + 1;                     // 1.6 MB
    int*   partials = cursor2 + NT2;                     // 784 B
    float* b1f     = (float*)(partials + 256);           // 256 B
    unsigned short* w2bf = (unsigned short*)(b1f + 64);  // 128 B (16B-aligned)
    float* b2fp    = (float*)(w2bf + 64);                // 16 B
    int*   flags   = (int*)(b2fp + 4);                   // 8 B

    unsigned short* vtab = p_src;   // alias: v-rows live here until nodemm

    {   // coopA: detect + CSR2 build + phased gather (one cooperative launch)
        void* xa = (void*)x;  void* eia = (void*)ei;
        void* w2a = (void*)W2; void* b1a = (void*)b1; void* b2a = (void*)b2;
        void* args[] = { &xa, &eia, &w2a, &b1a, &b2a,
                         (void*)&flags, (void*)&w2bf, (void*)&b1f, (void*)&b2fp,
                         (void*)&counts2, (void*)&off2, (void*)&cursor2,
                         (void*)&partials, (void*)&sarr, (void*)&earr,
                         (void*)&vtab };
        hipLaunchCooperativeKernel((void*)coopA_kernel, dim3(GRID_A), dim3(256),
                                   args, 0, stream);
    }

    nodemm_kernel<<<(N_NODES + 63) / 64, 256, 0, stream>>>(vtab, W_enc, b_enc, W1,
                                                           p_src, p_dst, b1f, flags);

    {   // coopB: phased edge scorer
        void* outa = d_out;
        void* args[] = { (void*)&p_src, (void*)&p_dst, (void*)&off2,
                         (void*)&sarr, (void*)&earr, (void*)&w2bf, (void*)&b2fp,
                         &outa, (void*)&flags };
        hipLaunchCooperativeKernel((void*)coopB_kernel, dim3(GRID_A), dim3(256),
                                   args, 0, stream);
    }
}

// Round 11
// 249.459 us; speedup vs baseline: 12.2445x; 12.2445x over previous
//
#include <hip/hip_runtime.h>
#include <hip/hip_bf16.h>

#define N_NODES 50000
#define N_EDGES 800000
#define D 64
#define VROWS 50048   // 782 tiles * 64 rows, rounded up for unmasked A-loads
#define NBLK 196      // ceil(N_NODES / 256)

typedef __hip_bfloat16 bf16;
typedef __bf16 bf16x8 __attribute__((ext_vector_type(8)));
typedef float  f32x4  __attribute__((ext_vector_type(4)));

__device__ __forceinline__ float bu2f(unsigned short u) {
    unsigned int w = ((unsigned int)u) << 16;
    return __builtin_bit_cast(float, w);
}
__device__ __forceinline__ unsigned short f2bu(float f) {
    bf16 h = __float2bfloat16(f);           // RTNE
    return __builtin_bit_cast(unsigned short, h);
}
__device__ __forceinline__ float ldf(const void* p, size_t i, bool f32mode) {
    if (f32mode) return ((const float*)p)[i];
    return bu2f(((const unsigned short*)p)[i]);
}
__device__ __forceinline__ void stf(void* p, size_t i, float v, bool f32mode) {
    if (f32mode) ((float*)p)[i] = v;
    else ((unsigned short*)p)[i] = f2bu(v);
}
__device__ __forceinline__ int ldidx(const int* ei, size_t e, int row, bool i64mode) {
    if (i64mode) return ei[((size_t)row * N_EDGES + e) * 2];  // low word, LE
    return ei[(size_t)row * N_EDGES + e];
}
__device__ __forceinline__ void unpack8(uint4 v, float* f) {
    f[0] = bu2f(v.x & 0xffff); f[1] = bu2f(v.x >> 16);
    f[2] = bu2f(v.y & 0xffff); f[3] = bu2f(v.y >> 16);
    f[4] = bu2f(v.z & 0xffff); f[5] = bu2f(v.z >> 16);
    f[6] = bu2f(v.w & 0xffff); f[7] = bu2f(v.w >> 16);
}

// ---------------------------------------------------------------------------
// Kernel 0: dtype detection (proven R2-R9), 1 wave.
// ---------------------------------------------------------------------------
__global__ void detect_kernel(const void* __restrict__ x,
                              const int* __restrict__ ei,
                              const void* __restrict__ W2,
                              const void* __restrict__ b1,
                              const void* __restrict__ b2,
                              int* __restrict__ flags,
                              unsigned short* __restrict__ w2bf,
                              float* __restrict__ b1f,
                              float* __restrict__ b2fp)
{
    int lane = threadIdx.x;   // <<<1,64>>>
    const unsigned short* u = (const unsigned short*)x;
    int weird = 0, zeros = 0;
    #pragma unroll
    for (int k = lane; k < 128; k += 64) {
        int ex = (u[2 * k] >> 7) & 0xFF;
        if (ex < 90 || ex > 160) ++weird;
        if (ei[2 * k + 1] == 0) ++zeros;
    }
    #pragma unroll
    for (int off = 1; off < 64; off <<= 1) {
        weird += __shfl_xor(weird, off, 64);
        zeros += __shfl_xor(zeros, off, 64);
    }
    bool f32m = (weird > 32);
    if (lane == 0) {
        flags[0] = f32m ? 1 : 0;
        flags[1] = (zeros > 120) ? 1 : 0;
        b2fp[0] = ldf(b2, 0, f32m);
    }
    w2bf[lane] = f2bu(ldf(W2, lane, f32m));
    b1f[lane]  = ldf(b1, lane, f32m);
}

// ---------------------------------------------------------------------------
// Kernel 1: in-degree histogram, XCD-sharded (proven R6).
// ---------------------------------------------------------------------------
__global__ __launch_bounds__(256) void hist_kernel(
    const int* __restrict__ ei, int* __restrict__ counts,
    const int* __restrict__ flags)
{
    bool i64m = flags[1] != 0;
    int grp   = blockIdx.x & 7;
    int e = (blockIdx.x >> 3) * 256 + threadIdx.x;
    if (e >= N_EDGES) return;
    int d = ldidx(ei, e, 1, i64m);
    if (((d >> 6) & 7) != grp) return;
    atomicAdd(&counts[d], 1);
}

// ---------------------------------------------------------------------------
// Kernels 2a/2b/2c: three-stage parallel exclusive scan (proven R5/R6).
// ---------------------------------------------------------------------------
__global__ __launch_bounds__(256) void scan1_kernel(
    const int* __restrict__ counts, int* __restrict__ partials)
{
    int tid = threadIdx.x;
    int i = blockIdx.x * 256 + tid;
    int v = (i < N_NODES) ? counts[i] : 0;
    #pragma unroll
    for (int off = 1; off < 64; off <<= 1) v += __shfl_xor(v, off, 64);
    __shared__ int ws[4];
    if ((tid & 63) == 0) ws[tid >> 6] = v;
    __syncthreads();
    if (tid == 0) partials[blockIdx.x] = ws[0] + ws[1] + ws[2] + ws[3];
}

__global__ __launch_bounds__(256) void scan2_kernel(
    int* __restrict__ partials, int* __restrict__ offsets)
{
    __shared__ int s[256];
    int tid = threadIdx.x;
    int v = (tid < NBLK) ? partials[tid] : 0;
    s[tid] = v;
    __syncthreads();
    for (int off = 1; off < 256; off <<= 1) {
        int t = (tid >= off) ? s[tid - off] : 0;
        __syncthreads();
        s[tid] += t;
        __syncthreads();
    }
    if (tid < NBLK) partials[tid] = s[tid] - v;
    if (tid == 255) offsets[N_NODES] = s[255];
}

__global__ __launch_bounds__(256) void scan3_kernel(
    const int* __restrict__ counts, const int* __restrict__ partials,
    int* __restrict__ offsets, int* __restrict__ cursor)
{
    __shared__ int s[256];
    int tid = threadIdx.x;
    int i = blockIdx.x * 256 + tid;
    int v = (i < N_NODES) ? counts[i] : 0;
    s[tid] = v;
    __syncthreads();
    for (int off = 1; off < 256; off <<= 1) {
        int t = (tid >= off) ? s[tid - off] : 0;
        __syncthreads();
        s[tid] += t;
        __syncthreads();
    }
    if (i < N_NODES) {
        int val = partials[blockIdx.x] + s[tid] - v;
        offsets[i] = val;
        cursor[i]  = val;
    }
}

// ---------------------------------------------------------------------------
// Kernel 3: bucket fill, XCD-sharded (proven R6). R11 delta: sarr is u16
// (src < 50000 < 2^16) — halves gather's index stream. earr stays int.
// ---------------------------------------------------------------------------
__global__ __launch_bounds__(256) void fill_kernel(
    const int* __restrict__ ei, int* __restrict__ cursor,
    unsigned short* __restrict__ sarr, int* __restrict__ earr,
    const int* __restrict__ flags)
{
    bool i64m = flags[1] != 0;
    int grp   = blockIdx.x & 7;
    int e = (blockIdx.x >> 3) * 256 + threadIdx.x;
    if (e >= N_EDGES) return;
    int d = ldidx(ei, e, 1, i64m);
    if (((d >> 6) & 7) != grp) return;
    int s = ldidx(ei, e, 0, i64m);
    int pos = atomicAdd(&cursor[d], 1);
    sarr[pos] = (unsigned short)s;
    earr[pos] = e;
}

// ---------------------------------------------------------------------------
// Kernel 4: gather — v[n] = x[n] + sum_{in-edges} x[src]. One wave per node,
// lane = feature, 8 independent accumulators, no LDS. (exact R6/R9 structure;
// u16 index stream)
// ---------------------------------------------------------------------------
__global__ __launch_bounds__(256) void gather_kernel(
    const void* __restrict__ x,
    const int* __restrict__ offsets, const unsigned short* __restrict__ sarr,
    unsigned short* __restrict__ vtab, const int* __restrict__ flags)
{
    bool f32m = flags[0] != 0;
    int w    = (blockIdx.x * 256 + threadIdx.x) >> 6;   // node id
    int lane = threadIdx.x & 63;
    if (w >= N_NODES) return;
    int beg = offsets[w], end = offsets[w + 1];

    float a0 = ldf(x, (size_t)w * D + lane, f32m);
    float a1 = 0.f, a2 = 0.f, a3 = 0.f, a4 = 0.f, a5 = 0.f, a6 = 0.f, a7 = 0.f;
    int j = beg;
    for (; j + 8 <= end; j += 8) {
        int s0 = sarr[j + 0], s1 = sarr[j + 1];
        int s2 = sarr[j + 2], s3 = sarr[j + 3];
        int s4 = sarr[j + 4], s5 = sarr[j + 5];
        int s6 = sarr[j + 6], s7 = sarr[j + 7];
        a0 += ldf(x, (size_t)s0 * D + lane, f32m);
        a1 += ldf(x, (size_t)s1 * D + lane, f32m);
        a2 += ldf(x, (size_t)s2 * D + lane, f32m);
        a3 += ldf(x, (size_t)s3 * D + lane, f32m);
        a4 += ldf(x, (size_t)s4 * D + lane, f32m);
        a5 += ldf(x, (size_t)s5 * D + lane, f32m);
        a6 += ldf(x, (size_t)s6 * D + lane, f32m);
        a7 += ldf(x, (size_t)s7 * D + lane, f32m);
    }
    for (; j < end; ++j)
        a0 += ldf(x, (size_t)sarr[j] * D + lane, f32m);
    float v = ((a0 + a1) + (a2 + a3)) + ((a4 + a5) + (a6 + a7));
    vtab[(size_t)w * D + lane] = f2bu(v);
}

// ---------------------------------------------------------------------------
// Kernel 5: MFMA node transform. One wave = 16 nodes. (exact R6/R9)
// vtab aliases p_src: each wave reads its own 16 rows before overwriting.
// ---------------------------------------------------------------------------
__global__ __launch_bounds__(256) void nodemm_kernel(
    const unsigned short* vtab,
    const void* __restrict__ W_enc, const void* __restrict__ b_enc,
    const void* __restrict__ W1,
    unsigned short* p_src, unsigned short* p_dst,
    const float* __restrict__ b1f, const int* __restrict__ flags)
{
    __shared__ unsigned short wtWe[64 * 72];
    __shared__ unsigned short wtWa[64 * 72];
    __shared__ unsigned short wtWb[64 * 72];
    __shared__ float benc[64];
    __shared__ unsigned short ebuf[4][16 * 72];

    bool f32m = flags[0] != 0;
    int tid = threadIdx.x;
    for (int t = tid; t < 4096; t += 256) {
        int i = t >> 6, j = t & 63;             // W[i][j], i=k(in), j=n(out)
        wtWe[j * 72 + i] = f2bu(ldf(W_enc, t, f32m));
        wtWa[j * 72 + i] = f2bu(ldf(W1, t, f32m));
        wtWb[j * 72 + i] = f2bu(ldf(W1, 4096 + t, f32m));
    }
    if (tid < 64) benc[tid] = ldf(b_enc, tid, f32m);
    __syncthreads();

    int wave = tid >> 6;
    int lane = tid & 63;
    int lo   = lane & 15;
    int quad = lane >> 4;
    unsigned short* eb = ebuf[wave];
    int base = blockIdx.x * 64 + wave * 16;

    bf16x8 av0 = *(const bf16x8*)&vtab[(size_t)(base + lo) * D + quad * 8];
    bf16x8 av1 = *(const bf16x8*)&vtab[(size_t)(base + lo) * D + 32 + quad * 8];

    f32x4 z = {0.f, 0.f, 0.f, 0.f};
    f32x4 acc1[4] = {z, z, z, z};
    #pragma unroll
    for (int nt = 0; nt < 4; ++nt) {
        bf16x8 b0  = *(const bf16x8*)&wtWe[(nt * 16 + lo) * 72 + quad * 8];
        bf16x8 b1v = *(const bf16x8*)&wtWe[(nt * 16 + lo) * 72 + 32 + quad * 8];
        acc1[nt] = __builtin_amdgcn_mfma_f32_16x16x32_bf16(av0, b0, acc1[nt], 0, 0, 0);
        acc1[nt] = __builtin_amdgcn_mfma_f32_16x16x32_bf16(av1, b1v, acc1[nt], 0, 0, 0);
    }
    #pragma unroll
    for (int nt = 0; nt < 4; ++nt) {
        float bias = benc[nt * 16 + lo];
        #pragma unroll
        for (int r = 0; r < 4; ++r) {
            int m = quad * 4 + r;
            float ev = fmaxf(acc1[nt][r] + bias, 0.f);
            eb[m * 72 + nt * 16 + lo] = f2bu(ev);
        }
    }

    bf16x8 ae0 = *(const bf16x8*)&eb[lo * 72 + quad * 8];
    bf16x8 ae1 = *(const bf16x8*)&eb[lo * 72 + 32 + quad * 8];

    f32x4 acc2[4] = {z, z, z, z};
    f32x4 acc3[4] = {z, z, z, z};
    #pragma unroll
    for (int nt = 0; nt < 4; ++nt) {
        bf16x8 ba0 = *(const bf16x8*)&wtWa[(nt * 16 + lo) * 72 + quad * 8];
        bf16x8 ba1 = *(const bf16x8*)&wtWa[(nt * 16 + lo) * 72 + 32 + quad * 8];
        bf16x8 bb0 = *(const bf16x8*)&wtWb[(nt * 16 + lo) * 72 + quad * 8];
        bf16x8 bb1 = *(const bf16x8*)&wtWb[(nt * 16 + lo) * 72 + 32 + quad * 8];
        acc2[nt] = __builtin_amdgcn_mfma_f32_16x16x32_bf16(ae0, ba0, acc2[nt], 0, 0, 0);
        acc2[nt] = __builtin_amdgcn_mfma_f32_16x16x32_bf16(ae1, ba1, acc2[nt], 0, 0, 0);
        acc3[nt] = __builtin_amdgcn_mfma_f32_16x16x32_bf16(ae0, bb0, acc3[nt], 0, 0, 0);
        acc3[nt] = __builtin_amdgcn_mfma_f32_16x16x32_bf16(ae1, bb1, acc3[nt], 0, 0, 0);
    }
    #pragma unroll
    for (int nt = 0; nt < 4; ++nt) {
        float b1v = b1f[nt * 16 + lo];
        #pragma unroll
        for (int r = 0; r < 4; ++r) {
            int node = base + quad * 4 + r;
            if (node < N_NODES) {
                size_t idx = (size_t)node * D + nt * 16 + lo;
                p_src[idx] = f2bu(acc2[nt][r] + b1v);   // fold b1
                p_dst[idx] = f2bu(acc3[nt][r]);
            }
        }
    }
}

// ---------------------------------------------------------------------------
// Kernel 6: edge scorer, dst-grouped. One wave per dst node; 8 lanes/edge.
// (exact R6/R9 structure; u16 sarr)
// ---------------------------------------------------------------------------
__global__ __launch_bounds__(256) void edge_kernel(
    const unsigned short* __restrict__ p_src,
    const unsigned short* __restrict__ p_dst,
    const int* __restrict__ offsets,
    const unsigned short* __restrict__ sarr, const int* __restrict__ earr,
    const unsigned short* __restrict__ w2bf, const float* __restrict__ b2fp,
    void* __restrict__ out, const int* __restrict__ flags)
{
    bool f32m = flags[0] != 0;
    int w    = (blockIdx.x * 256 + threadIdx.x) >> 6;   // dst node id
    int lane = threadIdx.x & 63;
    if (w >= N_NODES) return;
    int beg = offsets[w], end = offsets[w + 1];
    if (beg == end) return;

    int sub = lane & 7;    // feature chunk (8 feats)
    int g   = lane >> 3;   // edge slot within round

    uint4 pdv = ((const uint4*)p_dst)[(size_t)w * 8 + sub];
    uint4 w2v = ((const uint4*)w2bf)[sub];
    float pd[8], w2[8];
    unpack8(pdv, pd);
    unpack8(w2v, w2);
    float bb = b2fp[0];

    for (int pos0 = beg; pos0 < end; pos0 += 8) {
        int pos = pos0 + g;
        bool ok = pos < end;
        int idx = ok ? pos : beg;
        int s = sarr[idx];
        uint4 psv = ((const uint4*)p_src)[(size_t)s * 8 + sub];
        float ps[8];
        unpack8(psv, ps);
        float c = 0.f;
        #pragma unroll
        for (int i = 0; i < 8; ++i)
            c += fmaxf(ps[i] + pd[i], 0.f) * w2[i];
        c += __shfl_xor(c, 1, 64);
        c += __shfl_xor(c, 2, 64);
        c += __shfl_xor(c, 4, 64);
        if (sub == 0 && ok) {
            int eid = earr[pos];
            stf(out, eid, c + bb, f32m);
        }
    }
}

// ---------------------------------------------------------------------------
extern "C" void kernel_launch(void* const* d_in, const int* in_sizes, int n_in,
                              void* d_out, int out_size, void* d_ws, size_t ws_size,
                              hipStream_t stream)
{
    const void* x     = d_in[0];
    const int*  ei    = (const int*)d_in[1];
    const void* W_enc = d_in[2];
    const void* b_enc = d_in[3];
    const void* W1    = d_in[4];
    const void* b1    = d_in[5];
    const void* W2    = d_in[6];
    const void* b2    = d_in[7];

    const size_t NTv = (size_t)VROWS * D;   // 3,203,072 elements
    // ws layout (~18.2 MB):
    unsigned short* p_src = (unsigned short*)d_ws;       // 6.41 MB (aliases vtab)
    unsigned short* p_dst = p_src + NTv;                 // 6.41 MB
    unsigned short* sarr  = p_dst + NTv;                 // 1.6 MB (u16 src per pos)
    int*   earr    = (int*)(sarr + N_EDGES);             // 3.2 MB (eid per pos)
    float* b1f     = (float*)(earr + N_EDGES);           // 256 B
    unsigned short* w2bf = (unsigned short*)(b1f + 64);  // 128 B (16B-aligned)
    float* b2fp    = (float*)(w2bf + 64);                // 16 B
    int*   counts  = (int*)(b2fp + 4);                   // 200 KB
    int*   offsets = counts + N_NODES;                   // 200 KB (+1)
    int*   cursor  = offsets + N_NODES + 1;              // 200 KB
    int*   flags   = cursor + N_NODES;                   // 8 B
    int*   partials = flags + 2;                         // 1 KB

    unsigned short* vtab = p_src;   // alias: v-rows live here until nodemm

    detect_kernel<<<1, 64, 0, stream>>>(x, ei, W2, b1, b2, flags, w2bf, b1f, b2fp);
    hipMemsetAsync(counts, 0, (size_t)N_NODES * sizeof(int), stream);

    const int EB8 = ((N_EDGES + 255) / 256) * 8;
    hist_kernel<<<EB8, 256, 0, stream>>>(ei, counts, flags);
    scan1_kernel<<<NBLK, 256, 0, stream>>>(counts, partials);
    scan2_kernel<<<1, 256, 0, stream>>>(partials, offsets);
    scan3_kernel<<<NBLK, 256, 0, stream>>>(counts, partials, offsets, cursor);
    fill_kernel<<<EB8, 256, 0, stream>>>(ei, cursor, sarr, earr, flags);

    const int NWB = (N_NODES * 64 + 255) / 256;  // 12500 (1 wave/node)
    gather_kernel<<<NWB, 256, 0, stream>>>(x, offsets, sarr, vtab, flags);
    nodemm_kernel<<<(N_NODES + 63) / 64, 256, 0, stream>>>(vtab, W_enc, b_enc, W1,
                                                           p_src, p_dst, b1f, flags);
    edge_kernel<<<NWB, 256, 0, stream>>>(p_src, p_dst, offsets, sarr, earr,
                                         w2bf, b2fp, d_out, flags);
}